// Round 19
// baseline (765.585 us; speedup 1.0000x reference)
//
#include <hip/hip_runtime.h>
#include <math.h>

#define B_ 8
#define N_ 2048
#define C_ 256
#define TOK (B_*N_)
#define T_ 64
#define NCH (N_/T_)   // 32 chunks per batch

typedef __bf16 bf16x8 __attribute__((ext_vector_type(8)));
typedef float f32x4v __attribute__((ext_vector_type(4)));

__device__ __forceinline__ float dot4(const float4& a, const float4& b) {
  return (a.x*b.x + a.y*b.y) + (a.z*b.z + a.w*b.w);
}
__device__ __forceinline__ float rdlane(float x, int idx) {
  return __int_as_float(__builtin_amdgcn_readlane(__float_as_int(x), idx));
}
__device__ __forceinline__ float bf2f(unsigned short u) {
  return __uint_as_float(((unsigned)u) << 16);
}
__device__ __forceinline__ unsigned short f2bf(float f) {
  unsigned x = __float_as_uint(f);
  return (unsigned short)((x + 0x7FFFu + ((x >> 16) & 1u)) >> 16);
}

// ---------------- bf16 hi/lo split (proven R18) ----------------------------
__global__ __launch_bounds__(256) void split_bf(const float* __restrict__ src,
                                                unsigned short* __restrict__ hi,
                                                unsigned short* __restrict__ lo) {
  const size_t i = ((size_t)blockIdx.x * 256 + threadIdx.x) * 4;
  float4 v = *(const float4*)(src + i);
  ushort4 H, L;
  H.x = f2bf(v.x); H.y = f2bf(v.y); H.z = f2bf(v.z); H.w = f2bf(v.w);
  L.x = f2bf(v.x - bf2f(H.x));
  L.y = f2bf(v.y - bf2f(H.y));
  L.z = f2bf(v.z - bf2f(H.z));
  L.w = f2bf(v.w - bf2f(H.w));
  *(ushort4*)(hi + i) = H;
  *(ushort4*)(lo + i) = L;
}

// ---------------- bf16 hi/lo split, ONE matrix (proven R18) ----------------
__global__ __launch_bounds__(256) void split_w1(const float* __restrict__ W,
                                                unsigned short* __restrict__ wh,
                                                unsigned short* __restrict__ wl) {
  const size_t i = ((size_t)blockIdx.x * 256 + threadIdx.x) * 4;
  float4 v = *(const float4*)(W + i);
  ushort4 H, L;
  H.x = f2bf(v.x); H.y = f2bf(v.y); H.z = f2bf(v.z); H.w = f2bf(v.w);
  L.x = f2bf(v.x - bf2f(H.x));
  L.y = f2bf(v.y - bf2f(H.y));
  L.z = f2bf(v.z - bf2f(H.z));
  L.w = f2bf(v.w - bf2f(H.w));
  *(ushort4*)(wh + i) = H;
  *(ushort4*)(wl + i) = L;
}

// ---------------- MFMA projection (R18-proven core + template epilogue) ----
// Y = X @ W^T + b. bf16x3 split: y = xh*wh + xh*wl + xl*wh.
// grid (TOK/64), 4 waves; wave w: rows rowBase..+16 x 256 cols, 16 tiles.
// EPI: 0 = silu+l2norm, 1 = silu, 2 = sigmoid+row-mean (out size TOK),
//      3 = bias only. Direct pointer args; no dispatch machinery.
template<int EPI>
__global__ __launch_bounds__(256) void proj_tmpl(const unsigned short* __restrict__ xh,
                                                 const unsigned short* __restrict__ xl,
                                                 const unsigned short* __restrict__ wh,
                                                 const unsigned short* __restrict__ wl,
                                                 const float* __restrict__ bias,
                                                 float* __restrict__ out) {
  const int tid = threadIdx.x;
  const int l = tid & 63, w = tid >> 6;
  const int lc = l & 15, kg = l >> 4;
  const int rowBase = blockIdx.x * 64 + w * 16;
  const unsigned short* xhp = xh + (size_t)(rowBase + lc) * C_;
  const unsigned short* xlp = xl + (size_t)(rowBase + lc) * C_;

  f32x4v acc[16];
  #pragma unroll
  for (int nt = 0; nt < 16; ++nt) acc[nt] = (f32x4v){0.f, 0.f, 0.f, 0.f};

  for (int k0 = 0; k0 < C_; k0 += 32) {
    const int ko = k0 + kg * 8;
    bf16x8 ah = *reinterpret_cast<const bf16x8*>(xhp + ko);
    bf16x8 al = *reinterpret_cast<const bf16x8*>(xlp + ko);
    #pragma unroll
    for (int nt = 0; nt < 16; ++nt) {
      const size_t wo = (size_t)(nt * 16 + lc) * C_ + ko;
      bf16x8 bh = *reinterpret_cast<const bf16x8*>(wh + wo);
      bf16x8 bl = *reinterpret_cast<const bf16x8*>(wl + wo);
      acc[nt] = __builtin_amdgcn_mfma_f32_16x16x32_bf16(ah, bh, acc[nt], 0, 0, 0);
      acc[nt] = __builtin_amdgcn_mfma_f32_16x16x32_bf16(ah, bl, acc[nt], 0, 0, 0);
      acc[nt] = __builtin_amdgcn_mfma_f32_16x16x32_bf16(al, bh, acc[nt], 0, 0, 0);
    }
  }

  const int orow = rowBase + kg*4;    // + e (C/D row for this lane)

  if constexpr (EPI == 3) {
    #pragma unroll
    for (int nt = 0; nt < 16; ++nt) {
      const float bval = bias[nt*16 + lc];
      #pragma unroll
      for (int e = 0; e < 4; ++e)
        out[(size_t)(orow + e)*C_ + nt*16 + lc] = acc[nt][e] + bval;
    }
  } else if constexpr (EPI == 1) {
    #pragma unroll
    for (int nt = 0; nt < 16; ++nt) {
      const float bval = bias[nt*16 + lc];
      #pragma unroll
      for (int e = 0; e < 4; ++e) {
        float y = acc[nt][e] + bval;
        out[(size_t)(orow + e)*C_ + nt*16 + lc] = y / (1.f + __expf(-y));
      }
    }
  } else if constexpr (EPI == 0) {
    float part[4] = {0.f, 0.f, 0.f, 0.f};
    #pragma unroll
    for (int nt = 0; nt < 16; ++nt) {
      const float bval = bias[nt*16 + lc];
      #pragma unroll
      for (int e = 0; e < 4; ++e) {
        float y = acc[nt][e] + bval;
        float s = y / (1.f + __expf(-y));
        acc[nt][e] = s;
        part[e] += s * s;
      }
    }
    #pragma unroll
    for (int e = 0; e < 4; ++e) {
      float r = part[e];
      r += __shfl_xor(r, 1, 64);
      r += __shfl_xor(r, 2, 64);
      r += __shfl_xor(r, 4, 64);
      r += __shfl_xor(r, 8, 64);
      part[e] = 1.f / (sqrtf(r) + 1e-6f);
    }
    #pragma unroll
    for (int nt = 0; nt < 16; ++nt)
      #pragma unroll
      for (int e = 0; e < 4; ++e)
        out[(size_t)(orow + e)*C_ + nt*16 + lc] = acc[nt][e] * part[e];
  } else {  // EPI == 2: sigmoid row-mean -> out[orow+e] (out size TOK)
    float part[4] = {0.f, 0.f, 0.f, 0.f};
    #pragma unroll
    for (int nt = 0; nt < 16; ++nt) {
      const float bval = bias[nt*16 + lc];
      #pragma unroll
      for (int e = 0; e < 4; ++e) {
        float y = acc[nt][e] + bval;
        part[e] += 1.f / (1.f + __expf(-y));
      }
    }
    #pragma unroll
    for (int e = 0; e < 4; ++e) {
      float r = part[e];
      r += __shfl_xor(r, 1, 64);
      r += __shfl_xor(r, 2, 64);
      r += __shfl_xor(r, 4, 64);
      r += __shfl_xor(r, 8, 64);
      part[e] = r * (1.f / 256.f);
    }
    if (lc == 0) {
      #pragma unroll
      for (int e = 0; e < 4; ++e) out[orow + e] = part[e];
    }
  }
}

// ---------------- fused gram + WY solves + intra output (R18 verbatim) -----
__global__ __launch_bounds__(256) void chunk_prep(const float* __restrict__ kn,
                                                  const float* __restrict__ qn,
                                                  float* __restrict__ vO,
                                                  const float* __restrict__ Ag,
                                                  const float* __restrict__ Bg,
                                                  float* __restrict__ Ubuf,
                                                  float* __restrict__ qrm,
                                                  float* __restrict__ gbuf,
                                                  float* __restrict__ Oout) {
  __shared__ float Gl[64][68];
  __shared__ float Wl[64][68];
  __shared__ float pool[17408];
  __shared__ float gam[64], al[64], bl[64];
  float* Kp = pool;
  float* Qp = pool + 4096;
  const int bid = blockIdx.x;
  const int b = bid & 7, c = bid >> 3;
  const size_t ct0 = (size_t)b*N_ + (size_t)c*T_;
  const size_t base = ct0 * C_;
  const int tid = threadIdx.x;
  const int lane = tid & 63;
  const int sg = tid >> 6;

  if (tid < 64) { al[tid] = Ag[ct0 + tid]; bl[tid] = Bg[ct0 + tid]; }

  float accG[16], accQ[16];
  #pragma unroll
  for (int m = 0; m < 16; ++m) { accG[m] = 0.f; accQ[m] = 0.f; }
  for (int p = 0; p < 4; ++p) {
    __syncthreads();
    #pragma unroll
    for (int i = 0; i < 4; ++i) {
      int idx = i*256 + tid;
      int t = idx >> 4, u = idx & 15;
      int phys = (t*16 + (u ^ (t & 15))) * 4;
      *(float4*)&Kp[phys] = *(const float4*)(kn + base + (size_t)t*C_ + p*64 + u*4);
      *(float4*)&Qp[phys] = *(const float4*)(qn + base + (size_t)t*C_ + p*64 + u*4);
    }
    __syncthreads();
    #pragma unroll 4
    for (int j4 = 0; j4 < 16; ++j4) {
      float4 kt = *(const float4*)&Kp[(lane*16 + (j4 ^ (lane & 15))) * 4];
      float4 qt = *(const float4*)&Qp[(lane*16 + (j4 ^ (lane & 15))) * 4];
      #pragma unroll
      for (int m = 0; m < 16; ++m) {
        int r = sg*16 + m;
        float4 ks = *(const float4*)&Kp[(r*16 + (j4 ^ (r & 15))) * 4];
        accG[m] += dot4(kt, ks);
        accQ[m] += dot4(qt, ks);
      }
    }
  }
  __syncthreads();
  #pragma unroll
  for (int m = 0; m < 16; ++m) {
    int col = sg*16 + m;
    Gl[lane][col] = (col <  lane) ? accG[m] : 0.f;
    Wl[lane][col] = (col <= lane) ? accQ[m] : 0.f;
  }
  __syncthreads();
  if (tid == 0) {
    float g = 1.f;
    for (int s = 0; s < 64; ++s) { g *= al[s]; gam[s] = g; }
  }
  __syncthreads();
  if (tid < 64) gbuf[ct0 + tid] = gam[tid];
  __syncthreads();

  const int j = tid;
  float* const myrow = &pool[j * 68];

  for (int s = 0; s < 64; ++s) {
    float a0 = kn[base + (size_t)s*C_ + j], a1 = 0.f, a2 = 0.f, a3 = 0.f;
    for (int r4 = 0; r4 <= (s >> 2); ++r4) {
      float4 g = *(const float4*)&Gl[s][r4*4];
      float4 uu = *(const float4*)&myrow[r4*4];
      a0 -= g.x*uu.x; a1 -= g.y*uu.y; a2 -= g.z*uu.z; a3 -= g.w*uu.w;
    }
    float us = bl[s] * ((a0 + a1) + (a2 + a3));
    myrow[s] = us;
    Ubuf[base + (size_t)s*C_ + j] = us;
  }

  for (int t = 0; t < 64; ++t) {
    float a0 = qn[base + (size_t)t*C_ + j], a1 = 0.f, a2 = 0.f, a3 = 0.f;
    for (int s4 = 0; s4 < 16; ++s4) {
      float4 w = *(const float4*)&Wl[t][s4*4];
      float4 uu = *(const float4*)&myrow[s4*4];
      a0 -= w.x*uu.x; a1 -= w.y*uu.y; a2 -= w.z*uu.z; a3 -= w.w*uu.w;
    }
    qrm[base + (size_t)t*C_ + j] = (a0 + a1) + (a2 + a3);
  }

  __syncthreads();
  #pragma unroll
  for (int p2 = 0; p2 < 16; ++p2) {
    int idx = p2*256 + tid; int s = idx >> 6, r = idx & 63;
    float rs = gam[s] / gam[r];
    Gl[s][r] *= rs;
    Wl[s][r] *= rs;
  }
  __syncthreads();
  const float gT = gam[63];

  for (int s = 0; s < 64; ++s) {
    float a0 = vO[base + (size_t)s*C_ + j], a1 = 0.f, a2 = 0.f, a3 = 0.f;
    for (int r4 = 0; r4 <= (s >> 2); ++r4) {
      float4 g = *(const float4*)&Gl[s][r4*4];
      float4 yy = *(const float4*)&myrow[r4*4];
      a0 -= g.x*yy.x; a1 -= g.y*yy.y; a2 -= g.z*yy.z; a3 -= g.w*yy.w;
    }
    myrow[s] = bl[s] * ((a0 + a1) + (a2 + a3));
  }
  __syncthreads();
  for (int s4 = 0; s4 < 16; ++s4) {
    float4 yy = *(const float4*)&myrow[s4*4];
    float z0 = (gT / gam[s4*4+0]) * yy.x;
    float z1 = (gT / gam[s4*4+1]) * yy.y;
    float z2 = (gT / gam[s4*4+2]) * yy.z;
    float z3 = (gT / gam[s4*4+3]) * yy.w;
    *(float4*)&vO[base + (size_t)j*64 + s4*4] = make_float4(z0, z1, z2, z3);
  }
  for (int t = 0; t < 64; ++t) {
    float a0 = 0.f, a1 = 0.f, a2 = 0.f, a3 = 0.f;
    for (int s4 = 0; s4 < 16; ++s4) {
      float4 w = *(const float4*)&Wl[t][s4*4];
      float4 yy = *(const float4*)&myrow[s4*4];
      a0 += w.x*yy.x; a1 += w.y*yy.y; a2 += w.z*yy.z; a3 += w.w*yy.w;
    }
    Oout[base + (size_t)t*C_ + j] = (a0 + a1) + (a2 + a3);
  }
}

// ---------------- serial chunk scan (R18 verbatim) -------------------------
__global__ __launch_bounds__(256) void chunk_scan(const float* __restrict__ kn,
                                                  const float* __restrict__ qrm,
                                                  const float* __restrict__ urm,
                                                  const float* __restrict__ ztT,
                                                  const float* __restrict__ gbuf,
                                                  float* __restrict__ Oout) {
  __shared__ float Qs[16384];
  __shared__ float Us[16384];
  __shared__ float red[4*64*20];
  const int bid = blockIdx.x;
  const int b = bid & 7;
  const int wgrp = bid >> 3;
  const int tid = threadIdx.x;
  const int wave = tid >> 6, lane = tid & 63;
  const int i0 = wgrp*8;
  const int lx = lane & 15;

  float S_[8];
  #pragma unroll
  for (int r = 0; r < 8; ++r) S_[r] = 0.f;

  for (int ch = 0; ch < NCH; ++ch) {
    const size_t ct0 = (size_t)b*N_ + (size_t)ch*T_;
    const size_t base = ct0 * C_;

    #pragma unroll
    for (int i = 0; i < 16; ++i) {
      int g = i*256 + tid;
      int t = g >> 6, u = g & 63;
      int phys = (t*64 + (u ^ (t & 15))) * 4;
      *(float4*)&Qs[phys] = *(const float4*)(qrm + base + (size_t)g*4);
      *(float4*)&Us[phys] = *(const float4*)(urm + base + (size_t)g*4);
    }
    __syncthreads();                               // B1

    const float gv = gbuf[ct0 + lane];
    const float gT = rdlane(gv, 63);

    float oA[8], dB[8];
    #pragma unroll
    for (int r = 0; r < 8; ++r) { oA[r] = 0.f; dB[r] = 0.f; }
    #pragma unroll
    for (int uu = 0; uu < 16; ++uu) {
      const int u = (wave << 4) + uu;
      float4 qv = *(const float4*)&Qs[(lane*64 + (u ^ lx)) * 4];
      float4 uv = *(const float4*)&Us[(lane*64 + (u ^ lx)) * 4];
      #pragma unroll
      for (int m = 0; m < 4; ++m) {
        const int jl = 4*uu + m;
        const float qm = (m==0) ? qv.x : (m==1) ? qv.y : (m==2) ? qv.z : qv.w;
        const float um = (m==0) ? uv.x : (m==1) ? uv.y : (m==2) ? uv.z : uv.w;
        #pragma unroll
        for (int r = 0; r < 8; ++r) {
          const float sv = rdlane(S_[r], jl);
          oA[r] += sv * qm;
          dB[r] += sv * um;
        }
      }
    }
    {
      float* rp = &red[(wave*64 + lane) * 20];
      *(float4*)&rp[0]  = make_float4(oA[0], oA[1], oA[2], oA[3]);
      *(float4*)&rp[4]  = make_float4(oA[4], oA[5], oA[6], oA[7]);
      *(float4*)&rp[8]  = make_float4(dB[0], dB[1], dB[2], dB[3]);
      *(float4*)&rp[12] = make_float4(dB[4], dB[5], dB[6], dB[7]);
    }
    __syncthreads();                               // B2

    #pragma unroll
    for (int i = 0; i < 16; ++i) {
      int idx = (i*256 + tid) * 4;
      *(float4*)&Qs[idx] = *(const float4*)(kn + base + idx);
    }

    #pragma unroll
    for (int r = 0; r < 8; ++r) { oA[r] = 0.f; dB[r] = 0.f; }
    #pragma unroll
    for (int w2 = 0; w2 < 4; ++w2) {
      const float* rp = &red[(w2*64 + lane) * 20];
      float4 a = *(const float4*)&rp[0];
      float4 bq = *(const float4*)&rp[4];
      float4 cq = *(const float4*)&rp[8];
      float4 dq = *(const float4*)&rp[12];
      oA[0] += a.x;  oA[1] += a.y;  oA[2] += a.z;  oA[3] += a.w;
      oA[4] += bq.x; oA[5] += bq.y; oA[6] += bq.z; oA[7] += bq.w;
      dB[0] += cq.x; dB[1] += cq.y; dB[2] += cq.z; dB[3] += cq.w;
      dB[4] += dq.x; dB[5] += dq.y; dB[6] += dq.z; dB[7] += dq.w;
    }
    #pragma unroll
    for (int r = 0; r < 8; ++r) {
      const float z = ztT[base + (size_t)(i0 + r)*64 + lane];
      dB[r] = gT*dB[r] - z;
    }
    if (wave == 0) {
      float* orow = Oout + base + (size_t)lane*C_ + i0;
      float4 o0 = *(float4*)&orow[0];
      float4 o1 = *(float4*)&orow[4];
      o0.x += gv*oA[0]; o0.y += gv*oA[1]; o0.z += gv*oA[2]; o0.w += gv*oA[3];
      o1.x += gv*oA[4]; o1.y += gv*oA[5]; o1.z += gv*oA[6]; o1.w += gv*oA[7];
      *(float4*)&orow[0] = o0;
      *(float4*)&orow[4] = o1;
    }
    __syncthreads();                               // B3

    float acc[8];
    #pragma unroll
    for (int r = 0; r < 8; ++r) acc[r] = 0.f;
    const int jcol = (wave << 6) + lane;
    #pragma unroll 8
    for (int s = 0; s < 64; ++s) {
      const float kv = Qs[s*256 + jcol];
      #pragma unroll
      for (int r = 0; r < 8; ++r)
        acc[r] += rdlane(dB[r], s) * kv;
    }
    #pragma unroll
    for (int r = 0; r < 8; ++r) S_[r] = gT*S_[r] - acc[r];
    __syncthreads();                               // B4
  }
}

extern "C" void kernel_launch(void* const* d_in, const int* in_sizes, int n_in,
                              void* d_out, int out_size, void* d_ws, size_t ws_size,
                              hipStream_t stream) {
  const float* x  = (const float*)d_in[0];
  const float* Wq = (const float*)d_in[1];  const float* bq = (const float*)d_in[2];
  const float* Wk = (const float*)d_in[3];  const float* bk = (const float*)d_in[4];
  const float* Wv = (const float*)d_in[5];  const float* bv = (const float*)d_in[6];
  const float* Wa = (const float*)d_in[7];  const float* ba = (const float*)d_in[8];
  const float* Wb = (const float*)d_in[9];  const float* bb = (const float*)d_in[10];
  const float* Wo = (const float*)d_in[11]; const float* bo = (const float*)d_in[12];

  float* ws = (float*)d_ws;
  const size_t TC = (size_t)TOK * C_;
  float* qn   = ws;
  float* kn   = ws + TC;
  float* vO   = ws + 2*TC;             // V -> Z^T [i][s] (in place)
  float* Ag   = ws + 3*TC;
  float* Bg   = Ag + TOK;
  float* gbuf = Bg + TOK;
  float* Ubuf = gbuf + TOK;            // x-splits -> U -> Wo-splits
  float* qrm  = Ubuf + TC;             // Qtilde -> O-splits
  // footprint identical to R15/R18 (proven): 5*TC + 3*TOK floats

  unsigned short* xhi = (unsigned short*)Ubuf;     // TC ushorts
  unsigned short* xlo = xhi + TC;                  // TC ushorts (fills Ubuf)
  unsigned short* whd = (unsigned short*)d_out;    // 5 W-split pairs (1.25MB of 16MB)
  unsigned short* whiU = (unsigned short*)Ubuf;    // Wo splits after scan
  unsigned short* wloU = whiU + 65536;
  unsigned short* ohi = (unsigned short*)qrm;
  unsigned short* olo = ohi + TC;

  // 1. input split (into Ubuf region)
  split_bf<<<dim3(TC/1024), 256, 0, stream>>>(x, xhi, xlo);
  // 2. W splits for q,k,v,a,b (into d_out, dead until prep overwrites it)
  split_w1<<<dim3(64), 256, 0, stream>>>(Wq, whd + 0*131072, whd + 0*131072 + 65536);
  split_w1<<<dim3(64), 256, 0, stream>>>(Wk, whd + 1*131072, whd + 1*131072 + 65536);
  split_w1<<<dim3(64), 256, 0, stream>>>(Wv, whd + 2*131072, whd + 2*131072 + 65536);
  split_w1<<<dim3(64), 256, 0, stream>>>(Wa, whd + 3*131072, whd + 3*131072 + 65536);
  split_w1<<<dim3(64), 256, 0, stream>>>(Wb, whd + 4*131072, whd + 4*131072 + 65536);
  // 3. five MFMA projections (R18-proven structure, direct args)
  proj_tmpl<0><<<dim3(TOK/64), 256, 0, stream>>>(xhi, xlo, whd + 0*131072, whd + 0*131072 + 65536, bq, qn);
  proj_tmpl<0><<<dim3(TOK/64), 256, 0, stream>>>(xhi, xlo, whd + 1*131072, whd + 1*131072 + 65536, bk, kn);
  proj_tmpl<1><<<dim3(TOK/64), 256, 0, stream>>>(xhi, xlo, whd + 2*131072, whd + 2*131072 + 65536, bv, vO);
  proj_tmpl<2><<<dim3(TOK/64), 256, 0, stream>>>(xhi, xlo, whd + 3*131072, whd + 3*131072 + 65536, ba, Ag);
  proj_tmpl<2><<<dim3(TOK/64), 256, 0, stream>>>(xhi, xlo, whd + 4*131072, whd + 4*131072 + 65536, bb, Bg);
  // 4-5. WY prep + serial chunk scan (R18 verbatim)
  chunk_prep<<<dim3(256), 256, 0, stream>>>(kn, qn, vO, Ag, Bg, Ubuf, qrm, gbuf,
                                            (float*)d_out);
  chunk_scan<<<dim3(256), 256, 0, stream>>>(kn, qrm, Ubuf, vO, gbuf,
                                            (float*)d_out);
  // 6-8. final projection (R18 proven)
  split_w1<<<dim3(64), 256, 0, stream>>>(Wo, whiU, wloU);
  split_bf<<<dim3(TC/1024), 256, 0, stream>>>((const float*)d_out, ohi, olo);
  proj_tmpl<3><<<dim3(TOK/64), 256, 0, stream>>>(ohi, olo, whiU, wloU, bo,
                                                 (float*)d_out);
}

// Round 20
// 726.166 us; speedup vs baseline: 1.0543x; 1.0543x over previous
//
#include <hip/hip_runtime.h>
#include <math.h>

#define B_ 8
#define N_ 2048
#define C_ 256
#define TOK (B_*N_)
#define T_ 64
#define NCH (N_/T_)   // 32 chunks per batch

typedef __bf16 bf16x8 __attribute__((ext_vector_type(8)));
typedef float f32x4v __attribute__((ext_vector_type(4)));

__device__ __forceinline__ float dot4(const float4& a, const float4& b) {
  return (a.x*b.x + a.y*b.y) + (a.z*b.z + a.w*b.w);
}
__device__ __forceinline__ float rdlane(float x, int idx) {
  return __int_as_float(__builtin_amdgcn_readlane(__float_as_int(x), idx));
}
__device__ __forceinline__ float bf2f(unsigned short u) {
  return __uint_as_float(((unsigned)u) << 16);
}
__device__ __forceinline__ unsigned short f2bf(float f) {
  unsigned x = __float_as_uint(f);
  return (unsigned short)((x + 0x7FFFu + ((x >> 16) & 1u)) >> 16);
}

// ---------------- bf16 hi/lo split (proven R18) ----------------------------
__global__ __launch_bounds__(256) void split_bf(const float* __restrict__ src,
                                                unsigned short* __restrict__ hi,
                                                unsigned short* __restrict__ lo) {
  const size_t i = ((size_t)blockIdx.x * 256 + threadIdx.x) * 4;
  float4 v = *(const float4*)(src + i);
  ushort4 H, L;
  H.x = f2bf(v.x); H.y = f2bf(v.y); H.z = f2bf(v.z); H.w = f2bf(v.w);
  L.x = f2bf(v.x - bf2f(H.x));
  L.y = f2bf(v.y - bf2f(H.y));
  L.z = f2bf(v.z - bf2f(H.z));
  L.w = f2bf(v.w - bf2f(H.w));
  *(ushort4*)(hi + i) = H;
  *(ushort4*)(lo + i) = L;
}

// ---------------- bf16 hi/lo split, ONE matrix (proven R18) ----------------
__global__ __launch_bounds__(256) void split_w1(const float* __restrict__ W,
                                                unsigned short* __restrict__ wh,
                                                unsigned short* __restrict__ wl) {
  const size_t i = ((size_t)blockIdx.x * 256 + threadIdx.x) * 4;
  float4 v = *(const float4*)(W + i);
  ushort4 H, L;
  H.x = f2bf(v.x); H.y = f2bf(v.y); H.z = f2bf(v.z); H.w = f2bf(v.w);
  L.x = f2bf(v.x - bf2f(H.x));
  L.y = f2bf(v.y - bf2f(H.y));
  L.z = f2bf(v.z - bf2f(H.z));
  L.w = f2bf(v.w - bf2f(H.w));
  *(ushort4*)(wh + i) = H;
  *(ushort4*)(wl + i) = L;
}

// ---------------- MFMA projection v2: high-occupancy tiling ----------------
// Y = X @ W^T + b. bf16x3 split: y = xh*wh + xh*wl + xl*wh.
// grid TOK/16 = 1024 blocks (4/CU, 16 waves/CU vs R19's 4); block = 4 waves;
// wave w: rows rb..rb+16 x cols w*64..+64 (4 MFMA tiles). A-rows shared by
// all 4 waves (L1 reuse); per-wave loads drop 272 -> 80.
// Row reductions (l2norm / sigmoid-mean) cross waves via LDS redp + barrier.
// C/D (R18-proven): lane l, reg e -> row kg*4+e, col = w*64 + nt2*16 + lc.
template<int EPI>  // 0 silu+l2norm, 1 silu, 2 sigmoid+mean, 3 bias-only
__global__ __launch_bounds__(256) void proj_v2(const unsigned short* __restrict__ xh,
                                               const unsigned short* __restrict__ xl,
                                               const unsigned short* __restrict__ wh,
                                               const unsigned short* __restrict__ wl,
                                               const float* __restrict__ bias,
                                               float* __restrict__ out) {
  __shared__ float redp[4][20];
  const int tid = threadIdx.x;
  const int l = tid & 63, w = tid >> 6;
  const int lc = l & 15, kg = l >> 4;
  const int rb = blockIdx.x * 16;
  const unsigned short* xhp = xh + (size_t)(rb + lc) * C_;
  const unsigned short* xlp = xl + (size_t)(rb + lc) * C_;

  f32x4v acc[4];
  #pragma unroll
  for (int nt2 = 0; nt2 < 4; ++nt2) acc[nt2] = (f32x4v){0.f, 0.f, 0.f, 0.f};

  for (int k0 = 0; k0 < C_; k0 += 32) {
    const int ko = k0 + kg * 8;
    bf16x8 ah = *reinterpret_cast<const bf16x8*>(xhp + ko);
    bf16x8 al = *reinterpret_cast<const bf16x8*>(xlp + ko);
    #pragma unroll
    for (int nt2 = 0; nt2 < 4; ++nt2) {
      const size_t wo = (size_t)((w*4 + nt2) * 16 + lc) * C_ + ko;
      bf16x8 bh = *reinterpret_cast<const bf16x8*>(wh + wo);
      bf16x8 bl = *reinterpret_cast<const bf16x8*>(wl + wo);
      acc[nt2] = __builtin_amdgcn_mfma_f32_16x16x32_bf16(ah, bh, acc[nt2], 0, 0, 0);
      acc[nt2] = __builtin_amdgcn_mfma_f32_16x16x32_bf16(ah, bl, acc[nt2], 0, 0, 0);
      acc[nt2] = __builtin_amdgcn_mfma_f32_16x16x32_bf16(al, bh, acc[nt2], 0, 0, 0);
    }
  }

  const int row0 = kg * 4;       // + e : row within 16-row tile

  if constexpr (EPI == 3) {
    #pragma unroll
    for (int nt2 = 0; nt2 < 4; ++nt2) {
      const float bval = bias[w*64 + nt2*16 + lc];
      #pragma unroll
      for (int e = 0; e < 4; ++e)
        out[(size_t)(rb + row0 + e)*C_ + w*64 + nt2*16 + lc] = acc[nt2][e] + bval;
    }
  } else if constexpr (EPI == 1) {
    #pragma unroll
    for (int nt2 = 0; nt2 < 4; ++nt2) {
      const float bval = bias[w*64 + nt2*16 + lc];
      #pragma unroll
      for (int e = 0; e < 4; ++e) {
        float y = acc[nt2][e] + bval;
        out[(size_t)(rb + row0 + e)*C_ + w*64 + nt2*16 + lc] = y / (1.f + __expf(-y));
      }
    }
  } else if constexpr (EPI == 0) {
    float part[4] = {0.f, 0.f, 0.f, 0.f};
    #pragma unroll
    for (int nt2 = 0; nt2 < 4; ++nt2) {
      const float bval = bias[w*64 + nt2*16 + lc];
      #pragma unroll
      for (int e = 0; e < 4; ++e) {
        float y = acc[nt2][e] + bval;
        float s = y / (1.f + __expf(-y));
        acc[nt2][e] = s;
        part[e] += s * s;
      }
    }
    #pragma unroll
    for (int e = 0; e < 4; ++e) {
      float r = part[e];
      r += __shfl_xor(r, 1, 64);
      r += __shfl_xor(r, 2, 64);
      r += __shfl_xor(r, 4, 64);
      r += __shfl_xor(r, 8, 64);
      part[e] = r;                       // wave-partial row sum (64 cols)
    }
    if (lc == 0) {
      #pragma unroll
      for (int e = 0; e < 4; ++e) redp[w][row0 + e] = part[e];
    }
    __syncthreads();
    #pragma unroll
    for (int e = 0; e < 4; ++e) {
      float s = redp[0][row0+e] + redp[1][row0+e] + redp[2][row0+e] + redp[3][row0+e];
      part[e] = 1.f / (sqrtf(s) + 1e-6f);
    }
    #pragma unroll
    for (int nt2 = 0; nt2 < 4; ++nt2)
      #pragma unroll
      for (int e = 0; e < 4; ++e)
        out[(size_t)(rb + row0 + e)*C_ + w*64 + nt2*16 + lc] = acc[nt2][e] * part[e];
  } else {  // EPI == 2: sigmoid row-mean -> out[rb + row] (out size TOK)
    float part[4] = {0.f, 0.f, 0.f, 0.f};
    #pragma unroll
    for (int nt2 = 0; nt2 < 4; ++nt2) {
      const float bval = bias[w*64 + nt2*16 + lc];
      #pragma unroll
      for (int e = 0; e < 4; ++e) {
        float y = acc[nt2][e] + bval;
        part[e] += 1.f / (1.f + __expf(-y));
      }
    }
    #pragma unroll
    for (int e = 0; e < 4; ++e) {
      float r = part[e];
      r += __shfl_xor(r, 1, 64);
      r += __shfl_xor(r, 2, 64);
      r += __shfl_xor(r, 4, 64);
      r += __shfl_xor(r, 8, 64);
      part[e] = r;
    }
    if (lc == 0) {
      #pragma unroll
      for (int e = 0; e < 4; ++e) redp[w][row0 + e] = part[e];
    }
    __syncthreads();
    if (w == 0 && lc == 0) {
      #pragma unroll
      for (int e = 0; e < 4; ++e) {
        float s = redp[0][row0+e] + redp[1][row0+e] + redp[2][row0+e] + redp[3][row0+e];
        out[rb + row0 + e] = s * (1.f / 256.f);
      }
    }
  }
}

// ---------------- fused gram + WY solves + intra output (R18 verbatim) -----
__global__ __launch_bounds__(256) void chunk_prep(const float* __restrict__ kn,
                                                  const float* __restrict__ qn,
                                                  float* __restrict__ vO,
                                                  const float* __restrict__ Ag,
                                                  const float* __restrict__ Bg,
                                                  float* __restrict__ Ubuf,
                                                  float* __restrict__ qrm,
                                                  float* __restrict__ gbuf,
                                                  float* __restrict__ Oout) {
  __shared__ float Gl[64][68];
  __shared__ float Wl[64][68];
  __shared__ float pool[17408];
  __shared__ float gam[64], al[64], bl[64];
  float* Kp = pool;
  float* Qp = pool + 4096;
  const int bid = blockIdx.x;
  const int b = bid & 7, c = bid >> 3;
  const size_t ct0 = (size_t)b*N_ + (size_t)c*T_;
  const size_t base = ct0 * C_;
  const int tid = threadIdx.x;
  const int lane = tid & 63;
  const int sg = tid >> 6;

  if (tid < 64) { al[tid] = Ag[ct0 + tid]; bl[tid] = Bg[ct0 + tid]; }

  float accG[16], accQ[16];
  #pragma unroll
  for (int m = 0; m < 16; ++m) { accG[m] = 0.f; accQ[m] = 0.f; }
  for (int p = 0; p < 4; ++p) {
    __syncthreads();
    #pragma unroll
    for (int i = 0; i < 4; ++i) {
      int idx = i*256 + tid;
      int t = idx >> 4, u = idx & 15;
      int phys = (t*16 + (u ^ (t & 15))) * 4;
      *(float4*)&Kp[phys] = *(const float4*)(kn + base + (size_t)t*C_ + p*64 + u*4);
      *(float4*)&Qp[phys] = *(const float4*)(qn + base + (size_t)t*C_ + p*64 + u*4);
    }
    __syncthreads();
    #pragma unroll 4
    for (int j4 = 0; j4 < 16; ++j4) {
      float4 kt = *(const float4*)&Kp[(lane*16 + (j4 ^ (lane & 15))) * 4];
      float4 qt = *(const float4*)&Qp[(lane*16 + (j4 ^ (lane & 15))) * 4];
      #pragma unroll
      for (int m = 0; m < 16; ++m) {
        int r = sg*16 + m;
        float4 ks = *(const float4*)&Kp[(r*16 + (j4 ^ (r & 15))) * 4];
        accG[m] += dot4(kt, ks);
        accQ[m] += dot4(qt, ks);
      }
    }
  }
  __syncthreads();
  #pragma unroll
  for (int m = 0; m < 16; ++m) {
    int col = sg*16 + m;
    Gl[lane][col] = (col <  lane) ? accG[m] : 0.f;
    Wl[lane][col] = (col <= lane) ? accQ[m] : 0.f;
  }
  __syncthreads();
  if (tid == 0) {
    float g = 1.f;
    for (int s = 0; s < 64; ++s) { g *= al[s]; gam[s] = g; }
  }
  __syncthreads();
  if (tid < 64) gbuf[ct0 + tid] = gam[tid];
  __syncthreads();

  const int j = tid;
  float* const myrow = &pool[j * 68];

  for (int s = 0; s < 64; ++s) {
    float a0 = kn[base + (size_t)s*C_ + j], a1 = 0.f, a2 = 0.f, a3 = 0.f;
    for (int r4 = 0; r4 <= (s >> 2); ++r4) {
      float4 g = *(const float4*)&Gl[s][r4*4];
      float4 uu = *(const float4*)&myrow[r4*4];
      a0 -= g.x*uu.x; a1 -= g.y*uu.y; a2 -= g.z*uu.z; a3 -= g.w*uu.w;
    }
    float us = bl[s] * ((a0 + a1) + (a2 + a3));
    myrow[s] = us;
    Ubuf[base + (size_t)s*C_ + j] = us;
  }

  for (int t = 0; t < 64; ++t) {
    float a0 = qn[base + (size_t)t*C_ + j], a1 = 0.f, a2 = 0.f, a3 = 0.f;
    for (int s4 = 0; s4 < 16; ++s4) {
      float4 w = *(const float4*)&Wl[t][s4*4];
      float4 uu = *(const float4*)&myrow[s4*4];
      a0 -= w.x*uu.x; a1 -= w.y*uu.y; a2 -= w.z*uu.z; a3 -= w.w*uu.w;
    }
    qrm[base + (size_t)t*C_ + j] = (a0 + a1) + (a2 + a3);
  }

  __syncthreads();
  #pragma unroll
  for (int p2 = 0; p2 < 16; ++p2) {
    int idx = p2*256 + tid; int s = idx >> 6, r = idx & 63;
    float rs = gam[s] / gam[r];
    Gl[s][r] *= rs;
    Wl[s][r] *= rs;
  }
  __syncthreads();
  const float gT = gam[63];

  for (int s = 0; s < 64; ++s) {
    float a0 = vO[base + (size_t)s*C_ + j], a1 = 0.f, a2 = 0.f, a3 = 0.f;
    for (int r4 = 0; r4 <= (s >> 2); ++r4) {
      float4 g = *(const float4*)&Gl[s][r4*4];
      float4 yy = *(const float4*)&myrow[r4*4];
      a0 -= g.x*yy.x; a1 -= g.y*yy.y; a2 -= g.z*yy.z; a3 -= g.w*yy.w;
    }
    myrow[s] = bl[s] * ((a0 + a1) + (a2 + a3));
  }
  __syncthreads();
  for (int s4 = 0; s4 < 16; ++s4) {
    float4 yy = *(const float4*)&myrow[s4*4];
    float z0 = (gT / gam[s4*4+0]) * yy.x;
    float z1 = (gT / gam[s4*4+1]) * yy.y;
    float z2 = (gT / gam[s4*4+2]) * yy.z;
    float z3 = (gT / gam[s4*4+3]) * yy.w;
    *(float4*)&vO[base + (size_t)j*64 + s4*4] = make_float4(z0, z1, z2, z3);
  }
  for (int t = 0; t < 64; ++t) {
    float a0 = 0.f, a1 = 0.f, a2 = 0.f, a3 = 0.f;
    for (int s4 = 0; s4 < 16; ++s4) {
      float4 w = *(const float4*)&Wl[t][s4*4];
      float4 yy = *(const float4*)&myrow[s4*4];
      a0 += w.x*yy.x; a1 += w.y*yy.y; a2 += w.z*yy.z; a3 += w.w*yy.w;
    }
    Oout[base + (size_t)t*C_ + j] = (a0 + a1) + (a2 + a3);
  }
}

// ---------------- serial chunk scan (R18 verbatim) -------------------------
__global__ __launch_bounds__(256) void chunk_scan(const float* __restrict__ kn,
                                                  const float* __restrict__ qrm,
                                                  const float* __restrict__ urm,
                                                  const float* __restrict__ ztT,
                                                  const float* __restrict__ gbuf,
                                                  float* __restrict__ Oout) {
  __shared__ float Qs[16384];
  __shared__ float Us[16384];
  __shared__ float red[4*64*20];
  const int bid = blockIdx.x;
  const int b = bid & 7;
  const int wgrp = bid >> 3;
  const int tid = threadIdx.x;
  const int wave = tid >> 6, lane = tid & 63;
  const int i0 = wgrp*8;
  const int lx = lane & 15;

  float S_[8];
  #pragma unroll
  for (int r = 0; r < 8; ++r) S_[r] = 0.f;

  for (int ch = 0; ch < NCH; ++ch) {
    const size_t ct0 = (size_t)b*N_ + (size_t)ch*T_;
    const size_t base = ct0 * C_;

    #pragma unroll
    for (int i = 0; i < 16; ++i) {
      int g = i*256 + tid;
      int t = g >> 6, u = g & 63;
      int phys = (t*64 + (u ^ (t & 15))) * 4;
      *(float4*)&Qs[phys] = *(const float4*)(qrm + base + (size_t)g*4);
      *(float4*)&Us[phys] = *(const float4*)(urm + base + (size_t)g*4);
    }
    __syncthreads();                               // B1

    const float gv = gbuf[ct0 + lane];
    const float gT = rdlane(gv, 63);

    float oA[8], dB[8];
    #pragma unroll
    for (int r = 0; r < 8; ++r) { oA[r] = 0.f; dB[r] = 0.f; }
    #pragma unroll
    for (int uu = 0; uu < 16; ++uu) {
      const int u = (wave << 4) + uu;
      float4 qv = *(const float4*)&Qs[(lane*64 + (u ^ lx)) * 4];
      float4 uv = *(const float4*)&Us[(lane*64 + (u ^ lx)) * 4];
      #pragma unroll
      for (int m = 0; m < 4; ++m) {
        const int jl = 4*uu + m;
        const float qm = (m==0) ? qv.x : (m==1) ? qv.y : (m==2) ? qv.z : qv.w;
        const float um = (m==0) ? uv.x : (m==1) ? uv.y : (m==2) ? uv.z : uv.w;
        #pragma unroll
        for (int r = 0; r < 8; ++r) {
          const float sv = rdlane(S_[r], jl);
          oA[r] += sv * qm;
          dB[r] += sv * um;
        }
      }
    }
    {
      float* rp = &red[(wave*64 + lane) * 20];
      *(float4*)&rp[0]  = make_float4(oA[0], oA[1], oA[2], oA[3]);
      *(float4*)&rp[4]  = make_float4(oA[4], oA[5], oA[6], oA[7]);
      *(float4*)&rp[8]  = make_float4(dB[0], dB[1], dB[2], dB[3]);
      *(float4*)&rp[12] = make_float4(dB[4], dB[5], dB[6], dB[7]);
    }
    __syncthreads();                               // B2

    #pragma unroll
    for (int i = 0; i < 16; ++i) {
      int idx = (i*256 + tid) * 4;
      *(float4*)&Qs[idx] = *(const float4*)(kn + base + idx);
    }

    #pragma unroll
    for (int r = 0; r < 8; ++r) { oA[r] = 0.f; dB[r] = 0.f; }
    #pragma unroll
    for (int w2 = 0; w2 < 4; ++w2) {
      const float* rp = &red[(w2*64 + lane) * 20];
      float4 a = *(const float4*)&rp[0];
      float4 bq = *(const float4*)&rp[4];
      float4 cq = *(const float4*)&rp[8];
      float4 dq = *(const float4*)&rp[12];
      oA[0] += a.x;  oA[1] += a.y;  oA[2] += a.z;  oA[3] += a.w;
      oA[4] += bq.x; oA[5] += bq.y; oA[6] += bq.z; oA[7] += bq.w;
      dB[0] += cq.x; dB[1] += cq.y; dB[2] += cq.z; dB[3] += cq.w;
      dB[4] += dq.x; dB[5] += dq.y; dB[6] += dq.z; dB[7] += dq.w;
    }
    #pragma unroll
    for (int r = 0; r < 8; ++r) {
      const float z = ztT[base + (size_t)(i0 + r)*64 + lane];
      dB[r] = gT*dB[r] - z;
    }
    if (wave == 0) {
      float* orow = Oout + base + (size_t)lane*C_ + i0;
      float4 o0 = *(float4*)&orow[0];
      float4 o1 = *(float4*)&orow[4];
      o0.x += gv*oA[0]; o0.y += gv*oA[1]; o0.z += gv*oA[2]; o0.w += gv*oA[3];
      o1.x += gv*oA[4]; o1.y += gv*oA[5]; o1.z += gv*oA[6]; o1.w += gv*oA[7];
      *(float4*)&orow[0] = o0;
      *(float4*)&orow[4] = o1;
    }
    __syncthreads();                               // B3

    float acc[8];
    #pragma unroll
    for (int r = 0; r < 8; ++r) acc[r] = 0.f;
    const int jcol = (wave << 6) + lane;
    #pragma unroll 8
    for (int s = 0; s < 64; ++s) {
      const float kv = Qs[s*256 + jcol];
      #pragma unroll
      for (int r = 0; r < 8; ++r)
        acc[r] += rdlane(dB[r], s) * kv;
    }
    #pragma unroll
    for (int r = 0; r < 8; ++r) S_[r] = gT*S_[r] - acc[r];
    __syncthreads();                               // B4
  }
}

extern "C" void kernel_launch(void* const* d_in, const int* in_sizes, int n_in,
                              void* d_out, int out_size, void* d_ws, size_t ws_size,
                              hipStream_t stream) {
  const float* x  = (const float*)d_in[0];
  const float* Wq = (const float*)d_in[1];  const float* bq = (const float*)d_in[2];
  const float* Wk = (const float*)d_in[3];  const float* bk = (const float*)d_in[4];
  const float* Wv = (const float*)d_in[5];  const float* bv = (const float*)d_in[6];
  const float* Wa = (const float*)d_in[7];  const float* ba = (const float*)d_in[8];
  const float* Wb = (const float*)d_in[9];  const float* bb = (const float*)d_in[10];
  const float* Wo = (const float*)d_in[11]; const float* bo = (const float*)d_in[12];

  float* ws = (float*)d_ws;
  const size_t TC = (size_t)TOK * C_;
  float* qn   = ws;
  float* kn   = ws + TC;
  float* vO   = ws + 2*TC;             // V -> Z^T [i][s] (in place)
  float* Ag   = ws + 3*TC;
  float* Bg   = Ag + TOK;
  float* gbuf = Bg + TOK;
  float* Ubuf = gbuf + TOK;            // x-splits -> U -> Wo-splits
  float* qrm  = Ubuf + TC;             // Qtilde -> O-splits
  // footprint identical to R15/R18/R19 (proven): 5*TC + 3*TOK floats

  unsigned short* xhi = (unsigned short*)Ubuf;     // TC ushorts
  unsigned short* xlo = xhi + TC;                  // TC ushorts (fills Ubuf)
  unsigned short* whd = (unsigned short*)d_out;    // 5 W-split pairs (1.25MB of 16MB)
  unsigned short* whiU = (unsigned short*)Ubuf;    // Wo splits after scan
  unsigned short* wloU = whiU + 65536;
  unsigned short* ohi = (unsigned short*)qrm;
  unsigned short* olo = ohi + TC;

  // 1. input split
  split_bf<<<dim3(TC/1024), 256, 0, stream>>>(x, xhi, xlo);
  // 2. W splits for q,k,v,a,b (into d_out, dead until prep overwrites it)
  split_w1<<<dim3(64), 256, 0, stream>>>(Wq, whd + 0*131072, whd + 0*131072 + 65536);
  split_w1<<<dim3(64), 256, 0, stream>>>(Wk, whd + 1*131072, whd + 1*131072 + 65536);
  split_w1<<<dim3(64), 256, 0, stream>>>(Wv, whd + 2*131072, whd + 2*131072 + 65536);
  split_w1<<<dim3(64), 256, 0, stream>>>(Wa, whd + 3*131072, whd + 3*131072 + 65536);
  split_w1<<<dim3(64), 256, 0, stream>>>(Wb, whd + 4*131072, whd + 4*131072 + 65536);
  // 3. five MFMA projections (v2 tiling: 1024 blocks, 16 waves/CU)
  proj_v2<0><<<dim3(TOK/16), 256, 0, stream>>>(xhi, xlo, whd + 0*131072, whd + 0*131072 + 65536, bq, qn);
  proj_v2<0><<<dim3(TOK/16), 256, 0, stream>>>(xhi, xlo, whd + 1*131072, whd + 1*131072 + 65536, bk, kn);
  proj_v2<1><<<dim3(TOK/16), 256, 0, stream>>>(xhi, xlo, whd + 2*131072, whd + 2*131072 + 65536, bv, vO);
  proj_v2<2><<<dim3(TOK/16), 256, 0, stream>>>(xhi, xlo, whd + 3*131072, whd + 3*131072 + 65536, ba, Ag);
  proj_v2<2><<<dim3(TOK/16), 256, 0, stream>>>(xhi, xlo, whd + 4*131072, whd + 4*131072 + 65536, bb, Bg);
  // 4-5. WY prep + serial chunk scan (R18 verbatim)
  chunk_prep<<<dim3(256), 256, 0, stream>>>(kn, qn, vO, Ag, Bg, Ubuf, qrm, gbuf,
                                            (float*)d_out);
  chunk_scan<<<dim3(256), 256, 0, stream>>>(kn, qrm, Ubuf, vO, gbuf,
                                            (float*)d_out);
  // 6-8. final projection
  split_w1<<<dim3(64), 256, 0, stream>>>(Wo, whiU, wloU);
  split_bf<<<dim3(TC/1024), 256, 0, stream>>>((const float*)d_out, ohi, olo);
  proj_v2<3><<<dim3(TOK/16), 256, 0, stream>>>(ohi, olo, whiU, wloU, bo,
                                               (float*)d_out);
}

// Round 21
// 588.912 us; speedup vs baseline: 1.3000x; 1.2331x over previous
//
#include <hip/hip_runtime.h>
#include <math.h>

#define B_ 8
#define N_ 2048
#define C_ 256
#define TOK (B_*N_)
#define T_ 64
#define NCH (N_/T_)   // 32 chunks per batch

typedef __bf16 bf16x8 __attribute__((ext_vector_type(8)));
typedef float f32x4v __attribute__((ext_vector_type(4)));

__device__ __forceinline__ float dot4(const float4& a, const float4& b) {
  return (a.x*b.x + a.y*b.y) + (a.z*b.z + a.w*b.w);
}
__device__ __forceinline__ float rdlane(float x, int idx) {
  return __int_as_float(__builtin_amdgcn_readlane(__float_as_int(x), idx));
}
__device__ __forceinline__ float bf2f(unsigned short u) {
  return __uint_as_float(((unsigned)u) << 16);
}
__device__ __forceinline__ unsigned short f2bf(float f) {
  unsigned x = __float_as_uint(f);
  return (unsigned short)((x + 0x7FFFu + ((x >> 16) & 1u)) >> 16);
}

// ---------------- bf16 hi/lo split, FRAGMENT-PACKED ------------------------
// Packs element (row,k) of a [rows][256] f32 matrix into MFMA A/B fragment
// order: pos = ((  (row>>4)*8 + (k>>5) )*64 + ((k>>3)&3)*16 + (row&15))*8
//              + (k&7).
// A wave's fragment load is then ONE contiguous 1KB transaction (was 16).
__global__ __launch_bounds__(256) void split_pack(const float* __restrict__ src,
                                                  unsigned short* __restrict__ hi,
                                                  unsigned short* __restrict__ lo) {
  const size_t f = ((size_t)blockIdx.x * 256 + threadIdx.x) * 4;
  float4 v = *(const float4*)(src + f);
  const int row = (int)(f >> 8);
  const int k   = (int)(f & 255);
  const int R = row >> 4, lr = row & 15;
  const int ks = k >> 5, kg = (k >> 3) & 3, ki = k & 7;
  const size_t pos = ((((size_t)R*8 + ks)*64) + kg*16 + lr)*8 + ki;
  ushort4 H, L;
  H.x = f2bf(v.x); H.y = f2bf(v.y); H.z = f2bf(v.z); H.w = f2bf(v.w);
  L.x = f2bf(v.x - bf2f(H.x));
  L.y = f2bf(v.y - bf2f(H.y));
  L.z = f2bf(v.z - bf2f(H.z));
  L.w = f2bf(v.w - bf2f(H.w));
  *(ushort4*)(hi + pos) = H;
  *(ushort4*)(lo + pos) = L;
}

// ---------------- MFMA projection v3: packed fragments ---------------------
// Y = X @ W^T + b. bf16x3 split: y = xh*wh + xh*wl + xl*wh.
// grid TOK/16 (4 blocks/CU, 16 waves/CU); block = 4 waves; wave w: rows
// rb..rb+16 x cols w*64..+64 (4 tiles). All A/B loads are packed-contiguous.
// C/D (R18-proven): lane l, reg e -> row kg*4+e, col w*64 + nt2*16 + lc.
template<int EPI>  // 0 silu+l2norm, 1 silu, 2 sigmoid+mean, 3 bias-only
__global__ __launch_bounds__(256) void proj_v3(const unsigned short* __restrict__ xh,
                                               const unsigned short* __restrict__ xl,
                                               const unsigned short* __restrict__ wh,
                                               const unsigned short* __restrict__ wl,
                                               const float* __restrict__ bias,
                                               float* __restrict__ out) {
  __shared__ float redp[4][20];
  const int tid = threadIdx.x;
  const int l = tid & 63, w = tid >> 6;
  const int lc = l & 15, kg = l >> 4;
  const int rb = blockIdx.x * 16;
  const size_t Rbase = (size_t)blockIdx.x * 8;   // A-tile row-block * 8 ks

  f32x4v acc[4];
  #pragma unroll
  for (int nt2 = 0; nt2 < 4; ++nt2) acc[nt2] = (f32x4v){0.f, 0.f, 0.f, 0.f};

  #pragma unroll
  for (int ks = 0; ks < 8; ++ks) {
    const size_t apos = ((Rbase + ks)*64 + l)*8;
    bf16x8 ah = *reinterpret_cast<const bf16x8*>(xh + apos);
    bf16x8 al = *reinterpret_cast<const bf16x8*>(xl + apos);
    #pragma unroll
    for (int nt2 = 0; nt2 < 4; ++nt2) {
      const size_t bpos = (((size_t)(w*4 + nt2)*8 + ks)*64 + l)*8;
      bf16x8 bh = *reinterpret_cast<const bf16x8*>(wh + bpos);
      bf16x8 bl = *reinterpret_cast<const bf16x8*>(wl + bpos);
      acc[nt2] = __builtin_amdgcn_mfma_f32_16x16x32_bf16(ah, bh, acc[nt2], 0, 0, 0);
      acc[nt2] = __builtin_amdgcn_mfma_f32_16x16x32_bf16(ah, bl, acc[nt2], 0, 0, 0);
      acc[nt2] = __builtin_amdgcn_mfma_f32_16x16x32_bf16(al, bh, acc[nt2], 0, 0, 0);
    }
  }

  const int row0 = kg * 4;       // + e : row within 16-row tile

  if constexpr (EPI == 3) {
    #pragma unroll
    for (int nt2 = 0; nt2 < 4; ++nt2) {
      const float bval = bias[w*64 + nt2*16 + lc];
      #pragma unroll
      for (int e = 0; e < 4; ++e)
        out[(size_t)(rb + row0 + e)*C_ + w*64 + nt2*16 + lc] = acc[nt2][e] + bval;
    }
  } else if constexpr (EPI == 1) {
    #pragma unroll
    for (int nt2 = 0; nt2 < 4; ++nt2) {
      const float bval = bias[w*64 + nt2*16 + lc];
      #pragma unroll
      for (int e = 0; e < 4; ++e) {
        float y = acc[nt2][e] + bval;
        out[(size_t)(rb + row0 + e)*C_ + w*64 + nt2*16 + lc] = y / (1.f + __expf(-y));
      }
    }
  } else if constexpr (EPI == 0) {
    float part[4] = {0.f, 0.f, 0.f, 0.f};
    #pragma unroll
    for (int nt2 = 0; nt2 < 4; ++nt2) {
      const float bval = bias[w*64 + nt2*16 + lc];
      #pragma unroll
      for (int e = 0; e < 4; ++e) {
        float y = acc[nt2][e] + bval;
        float s = y / (1.f + __expf(-y));
        acc[nt2][e] = s;
        part[e] += s * s;
      }
    }
    #pragma unroll
    for (int e = 0; e < 4; ++e) {
      float r = part[e];
      r += __shfl_xor(r, 1, 64);
      r += __shfl_xor(r, 2, 64);
      r += __shfl_xor(r, 4, 64);
      r += __shfl_xor(r, 8, 64);
      part[e] = r;
    }
    if (lc == 0) {
      #pragma unroll
      for (int e = 0; e < 4; ++e) redp[w][row0 + e] = part[e];
    }
    __syncthreads();
    #pragma unroll
    for (int e = 0; e < 4; ++e) {
      float s = redp[0][row0+e] + redp[1][row0+e] + redp[2][row0+e] + redp[3][row0+e];
      part[e] = 1.f / (sqrtf(s) + 1e-6f);
    }
    #pragma unroll
    for (int nt2 = 0; nt2 < 4; ++nt2)
      #pragma unroll
      for (int e = 0; e < 4; ++e)
        out[(size_t)(rb + row0 + e)*C_ + w*64 + nt2*16 + lc] = acc[nt2][e] * part[e];
  } else {  // EPI == 2: sigmoid row-mean -> out[rb + row] (out size TOK)
    float part[4] = {0.f, 0.f, 0.f, 0.f};
    #pragma unroll
    for (int nt2 = 0; nt2 < 4; ++nt2) {
      const float bval = bias[w*64 + nt2*16 + lc];
      #pragma unroll
      for (int e = 0; e < 4; ++e) {
        float y = acc[nt2][e] + bval;
        part[e] += 1.f / (1.f + __expf(-y));
      }
    }
    #pragma unroll
    for (int e = 0; e < 4; ++e) {
      float r = part[e];
      r += __shfl_xor(r, 1, 64);
      r += __shfl_xor(r, 2, 64);
      r += __shfl_xor(r, 4, 64);
      r += __shfl_xor(r, 8, 64);
      part[e] = r;
    }
    if (lc == 0) {
      #pragma unroll
      for (int e = 0; e < 4; ++e) redp[w][row0 + e] = part[e];
    }
    __syncthreads();
    if (w == 0 && lc == 0) {
      #pragma unroll
      for (int e = 0; e < 4; ++e) {
        float s = redp[0][row0+e] + redp[1][row0+e] + redp[2][row0+e] + redp[3][row0+e];
        out[rb + row0 + e] = s * (1.f / 256.f);
      }
    }
  }
}

// ---------------- fused gram + WY solves + intra output (R18 verbatim) -----
__global__ __launch_bounds__(256) void chunk_prep(const float* __restrict__ kn,
                                                  const float* __restrict__ qn,
                                                  float* __restrict__ vO,
                                                  const float* __restrict__ Ag,
                                                  const float* __restrict__ Bg,
                                                  float* __restrict__ Ubuf,
                                                  float* __restrict__ qrm,
                                                  float* __restrict__ gbuf,
                                                  float* __restrict__ Oout) {
  __shared__ float Gl[64][68];
  __shared__ float Wl[64][68];
  __shared__ float pool[17408];
  __shared__ float gam[64], al[64], bl[64];
  float* Kp = pool;
  float* Qp = pool + 4096;
  const int bid = blockIdx.x;
  const int b = bid & 7, c = bid >> 3;
  const size_t ct0 = (size_t)b*N_ + (size_t)c*T_;
  const size_t base = ct0 * C_;
  const int tid = threadIdx.x;
  const int lane = tid & 63;
  const int sg = tid >> 6;

  if (tid < 64) { al[tid] = Ag[ct0 + tid]; bl[tid] = Bg[ct0 + tid]; }

  float accG[16], accQ[16];
  #pragma unroll
  for (int m = 0; m < 16; ++m) { accG[m] = 0.f; accQ[m] = 0.f; }
  for (int p = 0; p < 4; ++p) {
    __syncthreads();
    #pragma unroll
    for (int i = 0; i < 4; ++i) {
      int idx = i*256 + tid;
      int t = idx >> 4, u = idx & 15;
      int phys = (t*16 + (u ^ (t & 15))) * 4;
      *(float4*)&Kp[phys] = *(const float4*)(kn + base + (size_t)t*C_ + p*64 + u*4);
      *(float4*)&Qp[phys] = *(const float4*)(qn + base + (size_t)t*C_ + p*64 + u*4);
    }
    __syncthreads();
    #pragma unroll 4
    for (int j4 = 0; j4 < 16; ++j4) {
      float4 kt = *(const float4*)&Kp[(lane*16 + (j4 ^ (lane & 15))) * 4];
      float4 qt = *(const float4*)&Qp[(lane*16 + (j4 ^ (lane & 15))) * 4];
      #pragma unroll
      for (int m = 0; m < 16; ++m) {
        int r = sg*16 + m;
        float4 ks = *(const float4*)&Kp[(r*16 + (j4 ^ (r & 15))) * 4];
        accG[m] += dot4(kt, ks);
        accQ[m] += dot4(qt, ks);
      }
    }
  }
  __syncthreads();
  #pragma unroll
  for (int m = 0; m < 16; ++m) {
    int col = sg*16 + m;
    Gl[lane][col] = (col <  lane) ? accG[m] : 0.f;
    Wl[lane][col] = (col <= lane) ? accQ[m] : 0.f;
  }
  __syncthreads();
  if (tid == 0) {
    float g = 1.f;
    for (int s = 0; s < 64; ++s) { g *= al[s]; gam[s] = g; }
  }
  __syncthreads();
  if (tid < 64) gbuf[ct0 + tid] = gam[tid];
  __syncthreads();

  const int j = tid;
  float* const myrow = &pool[j * 68];

  for (int s = 0; s < 64; ++s) {
    float a0 = kn[base + (size_t)s*C_ + j], a1 = 0.f, a2 = 0.f, a3 = 0.f;
    for (int r4 = 0; r4 <= (s >> 2); ++r4) {
      float4 g = *(const float4*)&Gl[s][r4*4];
      float4 uu = *(const float4*)&myrow[r4*4];
      a0 -= g.x*uu.x; a1 -= g.y*uu.y; a2 -= g.z*uu.z; a3 -= g.w*uu.w;
    }
    float us = bl[s] * ((a0 + a1) + (a2 + a3));
    myrow[s] = us;
    Ubuf[base + (size_t)s*C_ + j] = us;
  }

  for (int t = 0; t < 64; ++t) {
    float a0 = qn[base + (size_t)t*C_ + j], a1 = 0.f, a2 = 0.f, a3 = 0.f;
    for (int s4 = 0; s4 < 16; ++s4) {
      float4 w = *(const float4*)&Wl[t][s4*4];
      float4 uu = *(const float4*)&myrow[s4*4];
      a0 -= w.x*uu.x; a1 -= w.y*uu.y; a2 -= w.z*uu.z; a3 -= w.w*uu.w;
    }
    qrm[base + (size_t)t*C_ + j] = (a0 + a1) + (a2 + a3);
  }

  __syncthreads();
  #pragma unroll
  for (int p2 = 0; p2 < 16; ++p2) {
    int idx = p2*256 + tid; int s = idx >> 6, r = idx & 63;
    float rs = gam[s] / gam[r];
    Gl[s][r] *= rs;
    Wl[s][r] *= rs;
  }
  __syncthreads();
  const float gT = gam[63];

  for (int s = 0; s < 64; ++s) {
    float a0 = vO[base + (size_t)s*C_ + j], a1 = 0.f, a2 = 0.f, a3 = 0.f;
    for (int r4 = 0; r4 <= (s >> 2); ++r4) {
      float4 g = *(const float4*)&Gl[s][r4*4];
      float4 yy = *(const float4*)&myrow[r4*4];
      a0 -= g.x*yy.x; a1 -= g.y*yy.y; a2 -= g.z*yy.z; a3 -= g.w*yy.w;
    }
    myrow[s] = bl[s] * ((a0 + a1) + (a2 + a3));
  }
  __syncthreads();
  for (int s4 = 0; s4 < 16; ++s4) {
    float4 yy = *(const float4*)&myrow[s4*4];
    float z0 = (gT / gam[s4*4+0]) * yy.x;
    float z1 = (gT / gam[s4*4+1]) * yy.y;
    float z2 = (gT / gam[s4*4+2]) * yy.z;
    float z3 = (gT / gam[s4*4+3]) * yy.w;
    *(float4*)&vO[base + (size_t)j*64 + s4*4] = make_float4(z0, z1, z2, z3);
  }
  for (int t = 0; t < 64; ++t) {
    float a0 = 0.f, a1 = 0.f, a2 = 0.f, a3 = 0.f;
    for (int s4 = 0; s4 < 16; ++s4) {
      float4 w = *(const float4*)&Wl[t][s4*4];
      float4 yy = *(const float4*)&myrow[s4*4];
      a0 += w.x*yy.x; a1 += w.y*yy.y; a2 += w.z*yy.z; a3 += w.w*yy.w;
    }
    Oout[base + (size_t)t*C_ + j] = (a0 + a1) + (a2 + a3);
  }
}

// ---------------- serial chunk scan (R18 verbatim) -------------------------
__global__ __launch_bounds__(256) void chunk_scan(const float* __restrict__ kn,
                                                  const float* __restrict__ qrm,
                                                  const float* __restrict__ urm,
                                                  const float* __restrict__ ztT,
                                                  const float* __restrict__ gbuf,
                                                  float* __restrict__ Oout) {
  __shared__ float Qs[16384];
  __shared__ float Us[16384];
  __shared__ float red[4*64*20];
  const int bid = blockIdx.x;
  const int b = bid & 7;
  const int wgrp = bid >> 3;
  const int tid = threadIdx.x;
  const int wave = tid >> 6, lane = tid & 63;
  const int i0 = wgrp*8;
  const int lx = lane & 15;

  float S_[8];
  #pragma unroll
  for (int r = 0; r < 8; ++r) S_[r] = 0.f;

  for (int ch = 0; ch < NCH; ++ch) {
    const size_t ct0 = (size_t)b*N_ + (size_t)ch*T_;
    const size_t base = ct0 * C_;

    #pragma unroll
    for (int i = 0; i < 16; ++i) {
      int g = i*256 + tid;
      int t = g >> 6, u = g & 63;
      int phys = (t*64 + (u ^ (t & 15))) * 4;
      *(float4*)&Qs[phys] = *(const float4*)(qrm + base + (size_t)g*4);
      *(float4*)&Us[phys] = *(const float4*)(urm + base + (size_t)g*4);
    }
    __syncthreads();                               // B1

    const float gv = gbuf[ct0 + lane];
    const float gT = rdlane(gv, 63);

    float oA[8], dB[8];
    #pragma unroll
    for (int r = 0; r < 8; ++r) { oA[r] = 0.f; dB[r] = 0.f; }
    #pragma unroll
    for (int uu = 0; uu < 16; ++uu) {
      const int u = (wave << 4) + uu;
      float4 qv = *(const float4*)&Qs[(lane*64 + (u ^ lx)) * 4];
      float4 uv = *(const float4*)&Us[(lane*64 + (u ^ lx)) * 4];
      #pragma unroll
      for (int m = 0; m < 4; ++m) {
        const int jl = 4*uu + m;
        const float qm = (m==0) ? qv.x : (m==1) ? qv.y : (m==2) ? qv.z : qv.w;
        const float um = (m==0) ? uv.x : (m==1) ? uv.y : (m==2) ? uv.z : uv.w;
        #pragma unroll
        for (int r = 0; r < 8; ++r) {
          const float sv = rdlane(S_[r], jl);
          oA[r] += sv * qm;
          dB[r] += sv * um;
        }
      }
    }
    {
      float* rp = &red[(wave*64 + lane) * 20];
      *(float4*)&rp[0]  = make_float4(oA[0], oA[1], oA[2], oA[3]);
      *(float4*)&rp[4]  = make_float4(oA[4], oA[5], oA[6], oA[7]);
      *(float4*)&rp[8]  = make_float4(dB[0], dB[1], dB[2], dB[3]);
      *(float4*)&rp[12] = make_float4(dB[4], dB[5], dB[6], dB[7]);
    }
    __syncthreads();                               // B2

    #pragma unroll
    for (int i = 0; i < 16; ++i) {
      int idx = (i*256 + tid) * 4;
      *(float4*)&Qs[idx] = *(const float4*)(kn + base + idx);
    }

    #pragma unroll
    for (int r = 0; r < 8; ++r) { oA[r] = 0.f; dB[r] = 0.f; }
    #pragma unroll
    for (int w2 = 0; w2 < 4; ++w2) {
      const float* rp = &red[(w2*64 + lane) * 20];
      float4 a = *(const float4*)&rp[0];
      float4 bq = *(const float4*)&rp[4];
      float4 cq = *(const float4*)&rp[8];
      float4 dq = *(const float4*)&rp[12];
      oA[0] += a.x;  oA[1] += a.y;  oA[2] += a.z;  oA[3] += a.w;
      oA[4] += bq.x; oA[5] += bq.y; oA[6] += bq.z; oA[7] += bq.w;
      dB[0] += cq.x; dB[1] += cq.y; dB[2] += cq.z; dB[3] += cq.w;
      dB[4] += dq.x; dB[5] += dq.y; dB[6] += dq.z; dB[7] += dq.w;
    }
    #pragma unroll
    for (int r = 0; r < 8; ++r) {
      const float z = ztT[base + (size_t)(i0 + r)*64 + lane];
      dB[r] = gT*dB[r] - z;
    }
    if (wave == 0) {
      float* orow = Oout + base + (size_t)lane*C_ + i0;
      float4 o0 = *(float4*)&orow[0];
      float4 o1 = *(float4*)&orow[4];
      o0.x += gv*oA[0]; o0.y += gv*oA[1]; o0.z += gv*oA[2]; o0.w += gv*oA[3];
      o1.x += gv*oA[4]; o1.y += gv*oA[5]; o1.z += gv*oA[6]; o1.w += gv*oA[7];
      *(float4*)&orow[0] = o0;
      *(float4*)&orow[4] = o1;
    }
    __syncthreads();                               // B3

    float acc[8];
    #pragma unroll
    for (int r = 0; r < 8; ++r) acc[r] = 0.f;
    const int jcol = (wave << 6) + lane;
    #pragma unroll 8
    for (int s = 0; s < 64; ++s) {
      const float kv = Qs[s*256 + jcol];
      #pragma unroll
      for (int r = 0; r < 8; ++r)
        acc[r] += rdlane(dB[r], s) * kv;
    }
    #pragma unroll
    for (int r = 0; r < 8; ++r) S_[r] = gT*S_[r] - acc[r];
    __syncthreads();                               // B4
  }
}

extern "C" void kernel_launch(void* const* d_in, const int* in_sizes, int n_in,
                              void* d_out, int out_size, void* d_ws, size_t ws_size,
                              hipStream_t stream) {
  const float* x  = (const float*)d_in[0];
  const float* Wq = (const float*)d_in[1];  const float* bq = (const float*)d_in[2];
  const float* Wk = (const float*)d_in[3];  const float* bk = (const float*)d_in[4];
  const float* Wv = (const float*)d_in[5];  const float* bv = (const float*)d_in[6];
  const float* Wa = (const float*)d_in[7];  const float* ba = (const float*)d_in[8];
  const float* Wb = (const float*)d_in[9];  const float* bb = (const float*)d_in[10];
  const float* Wo = (const float*)d_in[11]; const float* bo = (const float*)d_in[12];

  float* ws = (float*)d_ws;
  const size_t TC = (size_t)TOK * C_;
  float* qn   = ws;
  float* kn   = ws + TC;
  float* vO   = ws + 2*TC;             // V -> Z^T [i][s] (in place)
  float* Ag   = ws + 3*TC;
  float* Bg   = Ag + TOK;
  float* gbuf = Bg + TOK;
  float* Ubuf = gbuf + TOK;            // x-splits -> U -> Wo-splits
  float* qrm  = Ubuf + TC;             // Qtilde -> O-splits
  // footprint identical to R15/R18/R19/R20 (proven): 5*TC + 3*TOK floats

  unsigned short* xhi = (unsigned short*)Ubuf;     // packed, TC ushorts
  unsigned short* xlo = xhi + TC;
  unsigned short* whd = (unsigned short*)d_out;    // 5 packed W-split pairs
  unsigned short* whiU = (unsigned short*)Ubuf;    // Wo splits after scan
  unsigned short* wloU = whiU + 65536;
  unsigned short* ohi = (unsigned short*)qrm;
  unsigned short* olo = ohi + TC;

  // 1. input split (packed)
  split_pack<<<dim3(TC/1024), 256, 0, stream>>>(x, xhi, xlo);
  // 2. W splits (packed; into d_out, dead until prep overwrites it)
  split_pack<<<dim3(64), 256, 0, stream>>>(Wq, whd + 0*131072, whd + 0*131072 + 65536);
  split_pack<<<dim3(64), 256, 0, stream>>>(Wk, whd + 1*131072, whd + 1*131072 + 65536);
  split_pack<<<dim3(64), 256, 0, stream>>>(Wv, whd + 2*131072, whd + 2*131072 + 65536);
  split_pack<<<dim3(64), 256, 0, stream>>>(Wa, whd + 3*131072, whd + 3*131072 + 65536);
  split_pack<<<dim3(64), 256, 0, stream>>>(Wb, whd + 4*131072, whd + 4*131072 + 65536);
  // 3. five MFMA projections (packed fragments)
  proj_v3<0><<<dim3(TOK/16), 256, 0, stream>>>(xhi, xlo, whd + 0*131072, whd + 0*131072 + 65536, bq, qn);
  proj_v3<0><<<dim3(TOK/16), 256, 0, stream>>>(xhi, xlo, whd + 1*131072, whd + 1*131072 + 65536, bk, kn);
  proj_v3<1><<<dim3(TOK/16), 256, 0, stream>>>(xhi, xlo, whd + 2*131072, whd + 2*131072 + 65536, bv, vO);
  proj_v3<2><<<dim3(TOK/16), 256, 0, stream>>>(xhi, xlo, whd + 3*131072, whd + 3*131072 + 65536, ba, Ag);
  proj_v3<2><<<dim3(TOK/16), 256, 0, stream>>>(xhi, xlo, whd + 4*131072, whd + 4*131072 + 65536, bb, Bg);
  // 4-5. WY prep + serial chunk scan (R18 verbatim)
  chunk_prep<<<dim3(256), 256, 0, stream>>>(kn, qn, vO, Ag, Bg, Ubuf, qrm, gbuf,
                                            (float*)d_out);
  chunk_scan<<<dim3(256), 256, 0, stream>>>(kn, qrm, Ubuf, vO, gbuf,
                                            (float*)d_out);
  // 6-8. final projection (packed)
  split_pack<<<dim3(64), 256, 0, stream>>>(Wo, whiU, wloU);
  split_pack<<<dim3(TC/1024), 256, 0, stream>>>((const float*)d_out, ohi, olo);
  proj_v3<3><<<dim3(TOK/16), 256, 0, stream>>>(ohi, olo, whiU, wloU, bo,
                                               (float*)d_out);
}

// Round 22
// 568.174 us; speedup vs baseline: 1.3474x; 1.0365x over previous
//
#include <hip/hip_runtime.h>
#include <math.h>

#define B_ 8
#define N_ 2048
#define C_ 256
#define TOK (B_*N_)
#define T_ 64
#define NCH (N_/T_)   // 32 chunks per batch

typedef __bf16 bf16x8 __attribute__((ext_vector_type(8)));
typedef float f32x4v __attribute__((ext_vector_type(4)));

__device__ __forceinline__ float dot4(const float4& a, const float4& b) {
  return (a.x*b.x + a.y*b.y) + (a.z*b.z + a.w*b.w);
}
__device__ __forceinline__ float rdlane(float x, int idx) {
  return __int_as_float(__builtin_amdgcn_readlane(__float_as_int(x), idx));
}
__device__ __forceinline__ float bf2f(unsigned short u) {
  return __uint_as_float(((unsigned)u) << 16);
}
__device__ __forceinline__ unsigned short f2bf(float f) {
  unsigned x = __float_as_uint(f);
  return (unsigned short)((x + 0x7FFFu + ((x >> 16) & 1u)) >> 16);
}

// ---------------- bf16 hi/lo split, FRAGMENT-PACKED (R21 verbatim) ---------
__global__ __launch_bounds__(256) void split_pack(const float* __restrict__ src,
                                                  unsigned short* __restrict__ hi,
                                                  unsigned short* __restrict__ lo) {
  const size_t f = ((size_t)blockIdx.x * 256 + threadIdx.x) * 4;
  float4 v = *(const float4*)(src + f);
  const int row = (int)(f >> 8);
  const int k   = (int)(f & 255);
  const int R = row >> 4, lr = row & 15;
  const int ks = k >> 5, kg = (k >> 3) & 3, ki = k & 7;
  const size_t pos = ((((size_t)R*8 + ks)*64) + kg*16 + lr)*8 + ki;
  ushort4 H, L;
  H.x = f2bf(v.x); H.y = f2bf(v.y); H.z = f2bf(v.z); H.w = f2bf(v.w);
  L.x = f2bf(v.x - bf2f(H.x));
  L.y = f2bf(v.y - bf2f(H.y));
  L.z = f2bf(v.z - bf2f(H.z));
  L.w = f2bf(v.w - bf2f(H.w));
  *(ushort4*)(hi + pos) = H;
  *(ushort4*)(lo + pos) = L;
}

// ---------------- MFMA projection v3 (R21 verbatim) ------------------------
template<int EPI>  // 0 silu+l2norm, 1 silu, 2 sigmoid+mean, 3 bias-only
__global__ __launch_bounds__(256) void proj_v3(const unsigned short* __restrict__ xh,
                                               const unsigned short* __restrict__ xl,
                                               const unsigned short* __restrict__ wh,
                                               const unsigned short* __restrict__ wl,
                                               const float* __restrict__ bias,
                                               float* __restrict__ out) {
  __shared__ float redp[4][20];
  const int tid = threadIdx.x;
  const int l = tid & 63, w = tid >> 6;
  const int lc = l & 15, kg = l >> 4;
  const int rb = blockIdx.x * 16;
  const size_t Rbase = (size_t)blockIdx.x * 8;

  f32x4v acc[4];
  #pragma unroll
  for (int nt2 = 0; nt2 < 4; ++nt2) acc[nt2] = (f32x4v){0.f, 0.f, 0.f, 0.f};

  #pragma unroll
  for (int ks = 0; ks < 8; ++ks) {
    const size_t apos = ((Rbase + ks)*64 + l)*8;
    bf16x8 ah = *reinterpret_cast<const bf16x8*>(xh + apos);
    bf16x8 al = *reinterpret_cast<const bf16x8*>(xl + apos);
    #pragma unroll
    for (int nt2 = 0; nt2 < 4; ++nt2) {
      const size_t bpos = (((size_t)(w*4 + nt2)*8 + ks)*64 + l)*8;
      bf16x8 bh = *reinterpret_cast<const bf16x8*>(wh + bpos);
      bf16x8 bl = *reinterpret_cast<const bf16x8*>(wl + bpos);
      acc[nt2] = __builtin_amdgcn_mfma_f32_16x16x32_bf16(ah, bh, acc[nt2], 0, 0, 0);
      acc[nt2] = __builtin_amdgcn_mfma_f32_16x16x32_bf16(ah, bl, acc[nt2], 0, 0, 0);
      acc[nt2] = __builtin_amdgcn_mfma_f32_16x16x32_bf16(al, bh, acc[nt2], 0, 0, 0);
    }
  }

  const int row0 = kg * 4;

  if constexpr (EPI == 3) {
    #pragma unroll
    for (int nt2 = 0; nt2 < 4; ++nt2) {
      const float bval = bias[w*64 + nt2*16 + lc];
      #pragma unroll
      for (int e = 0; e < 4; ++e)
        out[(size_t)(rb + row0 + e)*C_ + w*64 + nt2*16 + lc] = acc[nt2][e] + bval;
    }
  } else if constexpr (EPI == 1) {
    #pragma unroll
    for (int nt2 = 0; nt2 < 4; ++nt2) {
      const float bval = bias[w*64 + nt2*16 + lc];
      #pragma unroll
      for (int e = 0; e < 4; ++e) {
        float y = acc[nt2][e] + bval;
        out[(size_t)(rb + row0 + e)*C_ + w*64 + nt2*16 + lc] = y / (1.f + __expf(-y));
      }
    }
  } else if constexpr (EPI == 0) {
    float part[4] = {0.f, 0.f, 0.f, 0.f};
    #pragma unroll
    for (int nt2 = 0; nt2 < 4; ++nt2) {
      const float bval = bias[w*64 + nt2*16 + lc];
      #pragma unroll
      for (int e = 0; e < 4; ++e) {
        float y = acc[nt2][e] + bval;
        float s = y / (1.f + __expf(-y));
        acc[nt2][e] = s;
        part[e] += s * s;
      }
    }
    #pragma unroll
    for (int e = 0; e < 4; ++e) {
      float r = part[e];
      r += __shfl_xor(r, 1, 64);
      r += __shfl_xor(r, 2, 64);
      r += __shfl_xor(r, 4, 64);
      r += __shfl_xor(r, 8, 64);
      part[e] = r;
    }
    if (lc == 0) {
      #pragma unroll
      for (int e = 0; e < 4; ++e) redp[w][row0 + e] = part[e];
    }
    __syncthreads();
    #pragma unroll
    for (int e = 0; e < 4; ++e) {
      float s = redp[0][row0+e] + redp[1][row0+e] + redp[2][row0+e] + redp[3][row0+e];
      part[e] = 1.f / (sqrtf(s) + 1e-6f);
    }
    #pragma unroll
    for (int nt2 = 0; nt2 < 4; ++nt2)
      #pragma unroll
      for (int e = 0; e < 4; ++e)
        out[(size_t)(rb + row0 + e)*C_ + w*64 + nt2*16 + lc] = acc[nt2][e] * part[e];
  } else {
    float part[4] = {0.f, 0.f, 0.f, 0.f};
    #pragma unroll
    for (int nt2 = 0; nt2 < 4; ++nt2) {
      const float bval = bias[w*64 + nt2*16 + lc];
      #pragma unroll
      for (int e = 0; e < 4; ++e) {
        float y = acc[nt2][e] + bval;
        part[e] += 1.f / (1.f + __expf(-y));
      }
    }
    #pragma unroll
    for (int e = 0; e < 4; ++e) {
      float r = part[e];
      r += __shfl_xor(r, 1, 64);
      r += __shfl_xor(r, 2, 64);
      r += __shfl_xor(r, 4, 64);
      r += __shfl_xor(r, 8, 64);
      part[e] = r;
    }
    if (lc == 0) {
      #pragma unroll
      for (int e = 0; e < 4; ++e) redp[w][row0 + e] = part[e];
    }
    __syncthreads();
    if (w == 0 && lc == 0) {
      #pragma unroll
      for (int e = 0; e < 4; ++e) {
        float s = redp[0][row0+e] + redp[1][row0+e] + redp[2][row0+e] + redp[3][row0+e];
        out[rb + row0 + e] = s * (1.f / 256.f);
      }
    }
  }
}

// ---------------- fused gram + WY solves + intra output (R18 verbatim) -----
__global__ __launch_bounds__(256) void chunk_prep(const float* __restrict__ kn,
                                                  const float* __restrict__ qn,
                                                  float* __restrict__ vO,
                                                  const float* __restrict__ Ag,
                                                  const float* __restrict__ Bg,
                                                  float* __restrict__ Ubuf,
                                                  float* __restrict__ qrm,
                                                  float* __restrict__ gbuf,
                                                  float* __restrict__ Oout) {
  __shared__ float Gl[64][68];
  __shared__ float Wl[64][68];
  __shared__ float pool[17408];
  __shared__ float gam[64], al[64], bl[64];
  float* Kp = pool;
  float* Qp = pool + 4096;
  const int bid = blockIdx.x;
  const int b = bid & 7, c = bid >> 3;
  const size_t ct0 = (size_t)b*N_ + (size_t)c*T_;
  const size_t base = ct0 * C_;
  const int tid = threadIdx.x;
  const int lane = tid & 63;
  const int sg = tid >> 6;

  if (tid < 64) { al[tid] = Ag[ct0 + tid]; bl[tid] = Bg[ct0 + tid]; }

  float accG[16], accQ[16];
  #pragma unroll
  for (int m = 0; m < 16; ++m) { accG[m] = 0.f; accQ[m] = 0.f; }
  for (int p = 0; p < 4; ++p) {
    __syncthreads();
    #pragma unroll
    for (int i = 0; i < 4; ++i) {
      int idx = i*256 + tid;
      int t = idx >> 4, u = idx & 15;
      int phys = (t*16 + (u ^ (t & 15))) * 4;
      *(float4*)&Kp[phys] = *(const float4*)(kn + base + (size_t)t*C_ + p*64 + u*4);
      *(float4*)&Qp[phys] = *(const float4*)(qn + base + (size_t)t*C_ + p*64 + u*4);
    }
    __syncthreads();
    #pragma unroll 4
    for (int j4 = 0; j4 < 16; ++j4) {
      float4 kt = *(const float4*)&Kp[(lane*16 + (j4 ^ (lane & 15))) * 4];
      float4 qt = *(const float4*)&Qp[(lane*16 + (j4 ^ (lane & 15))) * 4];
      #pragma unroll
      for (int m = 0; m < 16; ++m) {
        int r = sg*16 + m;
        float4 ks = *(const float4*)&Kp[(r*16 + (j4 ^ (r & 15))) * 4];
        accG[m] += dot4(kt, ks);
        accQ[m] += dot4(qt, ks);
      }
    }
  }
  __syncthreads();
  #pragma unroll
  for (int m = 0; m < 16; ++m) {
    int col = sg*16 + m;
    Gl[lane][col] = (col <  lane) ? accG[m] : 0.f;
    Wl[lane][col] = (col <= lane) ? accQ[m] : 0.f;
  }
  __syncthreads();
  if (tid == 0) {
    float g = 1.f;
    for (int s = 0; s < 64; ++s) { g *= al[s]; gam[s] = g; }
  }
  __syncthreads();
  if (tid < 64) gbuf[ct0 + tid] = gam[tid];
  __syncthreads();

  const int j = tid;
  float* const myrow = &pool[j * 68];

  for (int s = 0; s < 64; ++s) {
    float a0 = kn[base + (size_t)s*C_ + j], a1 = 0.f, a2 = 0.f, a3 = 0.f;
    for (int r4 = 0; r4 <= (s >> 2); ++r4) {
      float4 g = *(const float4*)&Gl[s][r4*4];
      float4 uu = *(const float4*)&myrow[r4*4];
      a0 -= g.x*uu.x; a1 -= g.y*uu.y; a2 -= g.z*uu.z; a3 -= g.w*uu.w;
    }
    float us = bl[s] * ((a0 + a1) + (a2 + a3));
    myrow[s] = us;
    Ubuf[base + (size_t)s*C_ + j] = us;
  }

  for (int t = 0; t < 64; ++t) {
    float a0 = qn[base + (size_t)t*C_ + j], a1 = 0.f, a2 = 0.f, a3 = 0.f;
    for (int s4 = 0; s4 < 16; ++s4) {
      float4 w = *(const float4*)&Wl[t][s4*4];
      float4 uu = *(const float4*)&myrow[s4*4];
      a0 -= w.x*uu.x; a1 -= w.y*uu.y; a2 -= w.z*uu.z; a3 -= w.w*uu.w;
    }
    qrm[base + (size_t)t*C_ + j] = (a0 + a1) + (a2 + a3);
  }

  __syncthreads();
  #pragma unroll
  for (int p2 = 0; p2 < 16; ++p2) {
    int idx = p2*256 + tid; int s = idx >> 6, r = idx & 63;
    float rs = gam[s] / gam[r];
    Gl[s][r] *= rs;
    Wl[s][r] *= rs;
  }
  __syncthreads();
  const float gT = gam[63];

  for (int s = 0; s < 64; ++s) {
    float a0 = vO[base + (size_t)s*C_ + j], a1 = 0.f, a2 = 0.f, a3 = 0.f;
    for (int r4 = 0; r4 <= (s >> 2); ++r4) {
      float4 g = *(const float4*)&Gl[s][r4*4];
      float4 yy = *(const float4*)&myrow[r4*4];
      a0 -= g.x*yy.x; a1 -= g.y*yy.y; a2 -= g.z*yy.z; a3 -= g.w*yy.w;
    }
    myrow[s] = bl[s] * ((a0 + a1) + (a2 + a3));
  }
  __syncthreads();
  for (int s4 = 0; s4 < 16; ++s4) {
    float4 yy = *(const float4*)&myrow[s4*4];
    float z0 = (gT / gam[s4*4+0]) * yy.x;
    float z1 = (gT / gam[s4*4+1]) * yy.y;
    float z2 = (gT / gam[s4*4+2]) * yy.z;
    float z3 = (gT / gam[s4*4+3]) * yy.w;
    *(float4*)&vO[base + (size_t)j*64 + s4*4] = make_float4(z0, z1, z2, z3);
  }
  for (int t = 0; t < 64; ++t) {
    float a0 = 0.f, a1 = 0.f, a2 = 0.f, a3 = 0.f;
    for (int s4 = 0; s4 < 16; ++s4) {
      float4 w = *(const float4*)&Wl[t][s4*4];
      float4 yy = *(const float4*)&myrow[s4*4];
      a0 += w.x*yy.x; a1 += w.y*yy.y; a2 += w.z*yy.z; a3 += w.w*yy.w;
    }
    Oout[base + (size_t)t*C_ + j] = (a0 + a1) + (a2 + a3);
  }
}

// ---------------- serial chunk scan v4: 8 waves (2/SIMD), j+row split ------
// grid 256 = (b = bid&7, wgrp = bid>>3); block = 512 = 8 waves.
// wave = (half = w>>2 owning rows i0h..i0h+3, jq = w&3 owning j-quarter).
// Same math/order as R15 (4-quarter j-split, same reduce order) but rows
// also split 2-way so waves/SIMD doubles 1 -> 2 (TLP to cover the phase
// latencies that pinned R15 at ~300us). red strided 12 floats (16B-aligned,
// 2 lanes/bank = conflict-free).
__global__ __launch_bounds__(512) void chunk_scan(const float* __restrict__ kn,
                                                  const float* __restrict__ qrm,
                                                  const float* __restrict__ urm,
                                                  const float* __restrict__ ztT,
                                                  const float* __restrict__ gbuf,
                                                  float* __restrict__ Oout) {
  __shared__ float Qs[16384];   // swizzled Q~ rows, later linear K
  __shared__ float Us[16384];   // swizzled U rows
  __shared__ float red[8*64*12];
  const int bid = blockIdx.x;
  const int b = bid & 7;
  const int wgrp = bid >> 3;
  const int tid = threadIdx.x;
  const int wave = tid >> 6, lane = tid & 63;
  const int half = wave >> 2, jq = wave & 3;
  const int i0h = wgrp*8 + half*4;    // this wave's 4 rows
  const int lx = lane & 15;

  float S_[4];
  #pragma unroll
  for (int r = 0; r < 4; ++r) S_[r] = 0.f;

  for (int ch = 0; ch < NCH; ++ch) {
    const size_t ct0 = (size_t)b*N_ + (size_t)ch*T_;
    const size_t base = ct0 * C_;

    // stage Q~/U row-major, 16B XOR swizzle (512 threads -> 8 units each)
    #pragma unroll
    for (int i = 0; i < 8; ++i) {
      int g = i*512 + tid;
      int t = g >> 6, u = g & 63;
      int phys = (t*64 + (u ^ (t & 15))) * 4;
      *(float4*)&Qs[phys] = *(const float4*)(qrm + base + (size_t)g*4);
      *(float4*)&Us[phys] = *(const float4*)(urm + base + (size_t)g*4);
    }
    __syncthreads();                               // B1

    const float gv = gbuf[ct0 + lane];
    const float gT = rdlane(gv, 63);

    // Pass A+B partials over this wave's j-quarter for its 4 rows
    float oA[4], dB[4];
    #pragma unroll
    for (int r = 0; r < 4; ++r) { oA[r] = 0.f; dB[r] = 0.f; }
    #pragma unroll
    for (int uu = 0; uu < 16; ++uu) {
      const int u = (jq << 4) + uu;                // logical 16B unit
      float4 qv = *(const float4*)&Qs[(lane*64 + (u ^ lx)) * 4];
      float4 uv = *(const float4*)&Us[(lane*64 + (u ^ lx)) * 4];
      #pragma unroll
      for (int m = 0; m < 4; ++m) {
        const int jl = 4*uu + m;                   // j_local within quarter
        const float qm = (m==0) ? qv.x : (m==1) ? qv.y : (m==2) ? qv.z : qv.w;
        const float um = (m==0) ? uv.x : (m==1) ? uv.y : (m==2) ? uv.z : uv.w;
        #pragma unroll
        for (int r = 0; r < 4; ++r) {
          const float sv = rdlane(S_[r], jl);
          oA[r] += sv * qm;
          dB[r] += sv * um;
        }
      }
    }
    // write partials (stride 12 floats = 48B, 16B-aligned, conflict-free)
    {
      float* rp = &red[(wave*64 + lane) * 12];
      *(float4*)&rp[0] = make_float4(oA[0], oA[1], oA[2], oA[3]);
      *(float4*)&rp[4] = make_float4(dB[0], dB[1], dB[2], dB[3]);
    }
    __syncthreads();                               // B2 (red ready; Qs reads done)

    // restage K (row-major linear) over the Qs region
    #pragma unroll
    for (int i = 0; i < 8; ++i) {
      int idx = (i*512 + tid) * 4;
      *(float4*)&Qs[idx] = *(const float4*)(kn + base + idx);
    }

    // cross-wave reduce over the 4 j-quarters of THIS half
    #pragma unroll
    for (int r = 0; r < 4; ++r) { oA[r] = 0.f; dB[r] = 0.f; }
    #pragma unroll
    for (int jq2 = 0; jq2 < 4; ++jq2) {
      const float* rp = &red[((half*4 + jq2)*64 + lane) * 12];
      float4 a = *(const float4*)&rp[0];
      float4 d = *(const float4*)&rp[4];
      oA[0] += a.x; oA[1] += a.y; oA[2] += a.z; oA[3] += a.w;
      dB[0] += d.x; dB[1] += d.y; dB[2] += d.z; dB[3] += d.w;
    }
    // cf[s=lane][r] = gT*dB - Z
    #pragma unroll
    for (int r = 0; r < 4; ++r) {
      const float z = ztT[base + (size_t)(i0h + r)*64 + lane];
      dB[r] = gT*dB[r] - z;
    }
    // O RMW: one wave per half (jq == 0), float4 per lane
    if (jq == 0) {
      float* orow = Oout + base + (size_t)lane*C_ + i0h;
      float4 o0 = *(float4*)&orow[0];
      o0.x += gv*oA[0]; o0.y += gv*oA[1]; o0.z += gv*oA[2]; o0.w += gv*oA[3];
      *(float4*)&orow[0] = o0;
    }
    __syncthreads();                               // B3 (K staged; red reads done)

    // Pass C: S'[r][j] = gT*S - sum_s cf[s][r]*K[s][j]; lane j = jq*64+lane
    float acc[4];
    #pragma unroll
    for (int r = 0; r < 4; ++r) acc[r] = 0.f;
    const int jcol = (jq << 6) + lane;
    #pragma unroll 8
    for (int s = 0; s < 64; ++s) {
      const float kv = Qs[s*256 + jcol];
      #pragma unroll
      for (int r = 0; r < 4; ++r)
        acc[r] += rdlane(dB[r], s) * kv;
    }
    #pragma unroll
    for (int r = 0; r < 4; ++r) S_[r] = gT*S_[r] - acc[r];
    __syncthreads();                               // B4 (C reads done)
  }
}

extern "C" void kernel_launch(void* const* d_in, const int* in_sizes, int n_in,
                              void* d_out, int out_size, void* d_ws, size_t ws_size,
                              hipStream_t stream) {
  const float* x  = (const float*)d_in[0];
  const float* Wq = (const float*)d_in[1];  const float* bq = (const float*)d_in[2];
  const float* Wk = (const float*)d_in[3];  const float* bk = (const float*)d_in[4];
  const float* Wv = (const float*)d_in[5];  const float* bv = (const float*)d_in[6];
  const float* Wa = (const float*)d_in[7];  const float* ba = (const float*)d_in[8];
  const float* Wb = (const float*)d_in[9];  const float* bb = (const float*)d_in[10];
  const float* Wo = (const float*)d_in[11]; const float* bo = (const float*)d_in[12];

  float* ws = (float*)d_ws;
  const size_t TC = (size_t)TOK * C_;
  float* qn   = ws;
  float* kn   = ws + TC;
  float* vO   = ws + 2*TC;             // V -> Z^T [i][s] (in place)
  float* Ag   = ws + 3*TC;
  float* Bg   = Ag + TOK;
  float* gbuf = Bg + TOK;
  float* Ubuf = gbuf + TOK;            // x-splits -> U -> Wo-splits
  float* qrm  = Ubuf + TC;             // Qtilde -> O-splits

  unsigned short* xhi = (unsigned short*)Ubuf;
  unsigned short* xlo = xhi + TC;
  unsigned short* whd = (unsigned short*)d_out;
  unsigned short* whiU = (unsigned short*)Ubuf;
  unsigned short* wloU = whiU + 65536;
  unsigned short* ohi = (unsigned short*)qrm;
  unsigned short* olo = ohi + TC;

  split_pack<<<dim3(TC/1024), 256, 0, stream>>>(x, xhi, xlo);
  split_pack<<<dim3(64), 256, 0, stream>>>(Wq, whd + 0*131072, whd + 0*131072 + 65536);
  split_pack<<<dim3(64), 256, 0, stream>>>(Wk, whd + 1*131072, whd + 1*131072 + 65536);
  split_pack<<<dim3(64), 256, 0, stream>>>(Wv, whd + 2*131072, whd + 2*131072 + 65536);
  split_pack<<<dim3(64), 256, 0, stream>>>(Wa, whd + 3*131072, whd + 3*131072 + 65536);
  split_pack<<<dim3(64), 256, 0, stream>>>(Wb, whd + 4*131072, whd + 4*131072 + 65536);
  proj_v3<0><<<dim3(TOK/16), 256, 0, stream>>>(xhi, xlo, whd + 0*131072, whd + 0*131072 + 65536, bq, qn);
  proj_v3<0><<<dim3(TOK/16), 256, 0, stream>>>(xhi, xlo, whd + 1*131072, whd + 1*131072 + 65536, bk, kn);
  proj_v3<1><<<dim3(TOK/16), 256, 0, stream>>>(xhi, xlo, whd + 2*131072, whd + 2*131072 + 65536, bv, vO);
  proj_v3<2><<<dim3(TOK/16), 256, 0, stream>>>(xhi, xlo, whd + 3*131072, whd + 3*131072 + 65536, ba, Ag);
  proj_v3<2><<<dim3(TOK/16), 256, 0, stream>>>(xhi, xlo, whd + 4*131072, whd + 4*131072 + 65536, bb, Bg);
  chunk_prep<<<dim3(256), 256, 0, stream>>>(kn, qn, vO, Ag, Bg, Ubuf, qrm, gbuf,
                                            (float*)d_out);
  chunk_scan<<<dim3(256), 512, 0, stream>>>(kn, qrm, Ubuf, vO, gbuf,
                                            (float*)d_out);
  split_pack<<<dim3(64), 256, 0, stream>>>(Wo, whiU, wloU);
  split_pack<<<dim3(TC/1024), 256, 0, stream>>>((const float*)d_out, ohi, olo);
  proj_v3<3><<<dim3(TOK/16), 256, 0, stream>>>(ohi, olo, whiU, wloU, bo,
                                               (float*)d_out);
}